// Round 7
// baseline (232.286 us; speedup 1.0000x reference)
//
#include <hip/hip_runtime.h>
#include <hip/hip_bf16.h>

typedef unsigned short u16;
typedef __attribute__((ext_vector_type(8))) short short8;
typedef __attribute__((ext_vector_type(4))) float f32x4;
typedef __attribute__((ext_vector_type(4))) unsigned short u16x4;

#define LOG2E 1.44269504088896340736f

// ---- helpers ---------------------------------------------------------------

__device__ __forceinline__ void gl_lds16(const void* g, void* l) {
  __builtin_amdgcn_global_load_lds(
      (__attribute__((address_space(1))) void*)g,
      (__attribute__((address_space(3))) void*)l, 16, 0, 0);
}

__device__ __forceinline__ u16 f2bf(float f) {
  union { float f; unsigned int i; } v;
  v.f = f;
  unsigned int r = v.i + 0x7fffu + ((v.i >> 16) & 1u);  // RNE
  return (u16)(r >> 16);
}

__device__ __forceinline__ unsigned int pack_bf2(float lo, float hi) {
  union { __hip_bfloat162 h2; unsigned int u; } c;
  c.h2 = __float22bfloat162_rn(make_float2(lo, hi));
  return c.u;
}

// ---- fp32 -> bf16 elementwise convert --------------------------------------

__global__ __launch_bounds__(256) void cvt_bf16(const float4* __restrict__ in,
                                                u16x4* __restrict__ out) {
  int i = blockIdx.x * 256 + threadIdx.x;
  float4 v = in[i];
  u16x4 o;
  o.x = f2bf(v.x); o.y = f2bf(v.y); o.z = f2bf(v.z); o.w = f2bf(v.w);
  out[i] = o;
}

// ---- weight transpose+convert: WT[n][k] = bf16(W[k][n]) --------------------

__global__ __launch_bounds__(256) void transpose_cvt(
    const float* __restrict__ W, u16* __restrict__ WT, int K, int N) {
  __shared__ u16 t[64][65];
  int r0 = blockIdx.y * 64, c0 = blockIdx.x * 64;
  int tx = threadIdx.x & 63, ty = threadIdx.x >> 6;
  for (int r = ty; r < 64; r += 4)
    t[r][tx] = f2bf(W[(size_t)(r0 + r) * N + c0 + tx]);
  __syncthreads();
  for (int r = ty; r < 64; r += 4)
    WT[(size_t)(c0 + r) * K + r0 + tx] = t[tx][r];
}

// ---- gemm_bt: C[M][N] = A[M][K] * Bt[N][K]^T + bias[N] ---------------------
// 128xBN tile (BN=128 or 64), BK=32, 4 waves, mfma 16x16x32 bf16

template <bool OUT_F32, int BN>
__global__ __launch_bounds__(256) void gemm_bt_kernel(
    const u16* __restrict__ A, const u16* __restrict__ Bt,
    const float* __restrict__ bias, void* __restrict__ Cout,
    int M, int N, int K) {
  constexpr int NBJ = BN / 32;         // wave n-frags (4 or 2)
  constexpr int CHUNKS = 8 + BN / 16;  // 16-row staging chunks (16 or 12)
  constexpr int PER_W = CHUNKS / 4;    // chunks per wave (4 or 3)
  __shared__ u16 As[128 * 32];
  __shared__ u16 Bs[BN * 32];
  int tid = threadIdx.x;
  int w = tid >> 6, lane = tid & 63, l15 = lane & 15, quad = lane >> 4;
  int m0 = blockIdx.y * 128, n0 = blockIdx.x * BN;
  int wm = (w & 1) * 64, wn = (w >> 1) * (BN / 2);

  f32x4 acc[4][NBJ];
#pragma unroll
  for (int i = 0; i < 4; ++i)
#pragma unroll
    for (int j = 0; j < NBJ; ++j) {
      f32x4 z = {0.f, 0.f, 0.f, 0.f};
      acc[i][j] = z;
    }

  int srow = lane >> 2;
  int scol = (lane & 3) * 8;

  for (int kt = 0; kt < K; kt += 32) {
    __syncthreads();
#pragma unroll
    for (int i = 0; i < PER_W; ++i) {
      int c = w * PER_W + i;
      if (c < 8) {
        int row = m0 + c * 16 + srow;
        gl_lds16(A + (size_t)row * K + kt + scol, As + c * 512);
      } else {
        int cc = c - 8;
        int row = n0 + cc * 16 + srow;
        gl_lds16(Bt + (size_t)row * K + kt + scol, Bs + cc * 512);
      }
    }
    __syncthreads();

    short8 af[4], bf[NBJ];
#pragma unroll
    for (int i = 0; i < 4; ++i)
      af[i] = *(const short8*)(As + (wm + i * 16 + l15) * 32 + quad * 8);
#pragma unroll
    for (int j = 0; j < NBJ; ++j)
      bf[j] = *(const short8*)(Bs + (wn + j * 16 + l15) * 32 + quad * 8);
#pragma unroll
    for (int i = 0; i < 4; ++i)
#pragma unroll
      for (int j = 0; j < NBJ; ++j)
        acc[i][j] = __builtin_amdgcn_mfma_f32_16x16x32_bf16(af[i], bf[j],
                                                            acc[i][j], 0, 0, 0);
  }

  float bv[NBJ];
#pragma unroll
  for (int j = 0; j < NBJ; ++j) bv[j] = bias[n0 + wn + j * 16 + l15];
#pragma unroll
  for (int i = 0; i < 4; ++i)
#pragma unroll
    for (int j = 0; j < NBJ; ++j) {
      int col = n0 + wn + j * 16 + l15;
#pragma unroll
      for (int r = 0; r < 4; ++r) {
        int row = m0 + wm + i * 16 + quad * 4 + r;
        float val = acc[i][j][r] + bv[j];
        if (OUT_F32)
          ((float*)Cout)[(size_t)row * N + col] = val;
        else
          ((u16*)Cout)[(size_t)row * N + col] = f2bf(val);
      }
    }
}

// ---- flash attention: paired q-tiles + wave-split-K, fixed-max softmax -----
// 512-thread blocks: waves 0-3 = half 0 (kt even), waves 4-7 = half 1 (kt odd).
// Fixed softmax shift (m=16) makes partials ADDITIVE: O = O0+O1, l = l0+l1 --
// merged in LDS at the end, no extra HBM traffic. Each half has private
// double-buffered K/V LDS; ONE barrier per coupled iteration (~17 vs 33).
// LDS arena (dwords): Ks h*4096+buf*2048 | Vt 8192+h*4096+buf*2048 | Ps 16384+w*512.

__global__ __launch_bounds__(512, 4) void flash_kernel(
    const u16* __restrict__ qkv, u16* __restrict__ att) {
  __shared__ unsigned int SH[20480];  // 80 KB

  int tid = threadIdx.x;
  int w = tid >> 6;       // 0..7
  int half = w >> 2;      // 0,1
  int wq = w & 3;         // q-quarter within strip
  int lane = tid & 63, l15 = lane & 15, quad = lane >> 4;
  int bx = blockIdx.x;
  int p = bx >> 5, bh = bx & 31, b = bh >> 4, h = bh & 15;
  const int qi[2] = {31 - p, p};
  const int kmax = qi[0];            // >= 16
  const int jmax = (kmax >> 1) + 1;  // coupled iterations

  const u16* base = qkv + (size_t)b * 2048 * 3072 + h * 64;
  const u16* kb = base + 1024;
  const u16* vb = base + 2048;

  // ones A-frag (row m=0) for the denominator tile
  short8 onesf;
#pragma unroll
  for (int j = 0; j < 8; ++j) onesf[j] = (l15 == 0) ? (short)0x3F80 : (short)0;

  // Q fragments (B-operand layout) direct from global
  short8 aq[2][2];
#pragma unroll
  for (int t = 0; t < 2; ++t) {
    const u16* qrow = base + (size_t)(qi[t] * 64 + wq * 16 + l15) * 3072;
#pragma unroll
    for (int ss = 0; ss < 2; ++ss)
      aq[t][ss] = *(const short8*)(qrow + ss * 32 + quad * 8);
  }

  // per-half staging mapping (256 threads each)
  int ht = tid & 255;
  const int krow = ht >> 3, h7 = ht & 7, kc16 = h7 * 8;
  const int vpr = ht >> 3, vd0 = h7 * 8;

  unsigned int* KsH = SH + half * 4096;         // [buf][2048]
  unsigned int* VtH = SH + 8192 + half * 4096;  // [buf][2048]
  unsigned int* Pw = SH + 16384 + w * 512;

  // tile kt=half -> buf0; prefetch tile half+2
  uint4 kr0 = *(const uint4*)(kb + (size_t)(half * 64 + krow) * 3072 + kc16);
  uint4 kr1 = *(const uint4*)(kb + (size_t)(half * 64 + krow + 32) * 3072 + kc16);
  uint4 vr0 = *(const uint4*)(vb + (size_t)(half * 64 + 2 * vpr) * 3072 + vd0);
  uint4 vr1 = *(const uint4*)(vb + (size_t)(half * 64 + 2 * vpr + 1) * 3072 + vd0);
  {
    *(uint4*)&KsH[32 * krow + ((4 * h7) ^ ((krow & 7) << 2))] = kr0;
    int r1 = krow + 32;
    *(uint4*)&KsH[32 * r1 + ((4 * h7) ^ ((r1 & 7) << 2))] = kr1;
    const u16* av = (const u16*)&vr0;
    const u16* bvp = (const u16*)&vr1;
#pragma unroll
    for (int j = 0; j < 8; ++j) {
      int d = vd0 + j;
      VtH[32 * d + (vpr ^ ((j ^ h7) << 2))] =
          (unsigned int)av[j] | ((unsigned int)bvp[j] << 16);
    }
  }
  {
    int kn = (half + 2) * 64;
    kr0 = *(const uint4*)(kb + (size_t)(kn + krow) * 3072 + kc16);
    kr1 = *(const uint4*)(kb + (size_t)(kn + krow + 32) * 3072 + kc16);
    vr0 = *(const uint4*)(vb + (size_t)(kn + 2 * vpr) * 3072 + vd0);
    vr1 = *(const uint4*)(vb + (size_t)(kn + 2 * vpr + 1) * 3072 + vd0);
  }

  f32x4 o[2][5];
#pragma unroll
  for (int t = 0; t < 2; ++t)
#pragma unroll
    for (int jd = 0; jd < 5; ++jd) {
      f32x4 z = {0.f, 0.f, 0.f, 0.f};
      o[t][jd] = z;
    }

  const int psw = (l15 & 7) << 2;
  const float kscale = 0.125f * LOG2E;
  const float fshift = 16.0f;

  for (int j = 0; j < jmax; ++j) {
    int kt = 2 * j + half;
    __syncthreads();
    if (kt + 2 <= kmax) {
      unsigned int* KsB = KsH + ((j + 1) & 1) * 2048;
      unsigned int* VtB = VtH + ((j + 1) & 1) * 2048;
      *(uint4*)&KsB[32 * krow + ((4 * h7) ^ ((krow & 7) << 2))] = kr0;
      int r1 = krow + 32;
      *(uint4*)&KsB[32 * r1 + ((4 * h7) ^ ((r1 & 7) << 2))] = kr1;
      const u16* av = (const u16*)&vr0;
      const u16* bvp = (const u16*)&vr1;
#pragma unroll
      for (int jj = 0; jj < 8; ++jj) {
        int d = vd0 + jj;
        VtB[32 * d + (vpr ^ ((jj ^ h7) << 2))] =
            (unsigned int)av[jj] | ((unsigned int)bvp[jj] << 16);
      }
    }
    if (kt + 4 <= kmax) {
      int kn = (kt + 4) * 64;
      kr0 = *(const uint4*)(kb + (size_t)(kn + krow) * 3072 + kc16);
      kr1 = *(const uint4*)(kb + (size_t)(kn + krow + 32) * 3072 + kc16);
      vr0 = *(const uint4*)(vb + (size_t)(kn + 2 * vpr) * 3072 + vd0);
      vr1 = *(const uint4*)(vb + (size_t)(kn + 2 * vpr + 1) * 3072 + vd0);
    }
    if (kt <= kmax) {
      const unsigned int* Kb = KsH + (j & 1) * 2048;
      const unsigned int* Vb = VtH + (j & 1) * 2048;

#pragma unroll
      for (int t = 0; t < 2; ++t) {
        if (kt > qi[t]) continue;  // wave-uniform

        // S^T = K Q^T (col = q = l15, row = key)
        f32x4 s[4];
#pragma unroll
        for (int jn = 0; jn < 4; ++jn) {
          f32x4 z = {0.f, 0.f, 0.f, 0.f};
          s[jn] = z;
        }
#pragma unroll
        for (int ss = 0; ss < 2; ++ss)
#pragma unroll
          for (int jn = 0; jn < 4; ++jn) {
            int row = jn * 16 + l15;
            short8 bk = *(const short8*)&Kb[32 * row + ((16 * ss + 4 * quad) ^
                                                        ((row & 7) << 2))];
            s[jn] = __builtin_amdgcn_mfma_f32_16x16x32_bf16(bk, aq[t][ss],
                                                            s[jn], 0, 0, 0);
          }

        // P = exp2(s*kscale - 16), diagonal-masked
        bool diag = (kt == qi[t]);
        int qloc = wq * 16 + l15;
#pragma unroll
        for (int jn = 0; jn < 4; ++jn) {
          float pv[4];
#pragma unroll
          for (int r = 0; r < 4; ++r) {
            float sv = s[jn][r];
            if (diag && (jn * 16 + quad * 4 + r > qloc)) sv = -1e30f;
            pv[r] = exp2f(fmaf(sv, kscale, -fshift));
          }
          uint2 dd = make_uint2(pack_bf2(pv[0], pv[1]), pack_bf2(pv[2], pv[3]));
          *(uint2*)&Pw[32 * l15 + (((jn << 3) + (quad << 1)) ^ psw)] = dd;
        }

        // O^T += Vt P^T (+ ones-frag tile accumulates l)
#pragma unroll
        for (int ss = 0; ss < 2; ++ss) {
          short8 pf = *(const short8*)&Pw[32 * l15 +
                                          (((ss << 4) + (quad << 2)) ^ psw)];
#pragma unroll
          for (int jd = 0; jd < 4; ++jd) {
            int vrow = jd * 16 + l15;
            int f = (vrow & 7) ^ ((vrow >> 3) & 7);
            short8 bvv = *(const short8*)&Vb[32 * vrow + (((ss << 4) +
                                                           (quad << 2)) ^
                                                          (f << 2))];
            o[t][jd] = __builtin_amdgcn_mfma_f32_16x16x32_bf16(bvv, pf,
                                                               o[t][jd], 0, 0, 0);
          }
          o[t][4] = __builtin_amdgcn_mfma_f32_16x16x32_bf16(onesf, pf, o[t][4],
                                                            0, 0, 0);
        }
      }
    }
  }

  // ---- in-LDS merge of the two halves (partials are additive) ----
  __syncthreads();  // all compute done; safe to clobber K/V arena
  float* OM = (float*)SH;            // [t][q][68] floats
  float* LM = (float*)(SH + 8704);   // [t*64+q]
  if (half == 0) {
#pragma unroll
    for (int t = 0; t < 2; ++t) {
      int q = wq * 16 + l15;
#pragma unroll
      for (int jd = 0; jd < 4; ++jd)
        *(float4*)&OM[((size_t)t * 64 + q) * 68 + jd * 16 + quad * 4] =
            *(float4*)&o[t][jd];
      if (quad == 0) LM[t * 64 + q] = o[t][4][0];
    }
  }
  __syncthreads();
  if (half == 1) {
#pragma unroll
    for (int t = 0; t < 2; ++t) {
      int q = wq * 16 + l15;
      float lr = __shfl(o[t][4][0], l15, 64) + LM[t * 64 + q];
      float inv = 1.f / lr;
      size_t row = (size_t)b * 2048 + qi[t] * 64 + q;
      u16* orow = att + row * 1024 + h * 64 + quad * 4;
#pragma unroll
      for (int jd = 0; jd < 4; ++jd) {
        float4 pa = *(float4*)&OM[((size_t)t * 64 + q) * 68 + jd * 16 + quad * 4];
        uint2 dd = make_uint2(pack_bf2((o[t][jd][0] + pa.x) * inv,
                                       (o[t][jd][1] + pa.y) * inv),
                              pack_bf2((o[t][jd][2] + pa.z) * inv,
                                       (o[t][jd][3] + pa.w) * inv));
        *(uint2*)(orow + jd * 16) = dd;
      }
    }
  }
}

// ---- launch ----------------------------------------------------------------

extern "C" void kernel_launch(void* const* d_in, const int* in_sizes, int n_in,
                              void* d_out, int out_size, void* d_ws,
                              size_t ws_size, hipStream_t stream) {
  const float* x = (const float*)d_in[0];
  const float* Wqkv = (const float*)d_in[1];
  const float* bqkv = (const float*)d_in[2];
  const float* Wout = (const float*)d_in[3];
  const float* bout = (const float*)d_in[4];
  float* out = (float*)d_out;

  char* ws = (char*)d_ws;
  u16* WqkvT = (u16*)(ws);            // [3072][1024] bf16
  u16* WoutT = (u16*)(ws + 6291456);  // [1024][1024] bf16
  u16* qkv = (u16*)(ws + 8388608);    // [4096][3072] bf16
  u16* attn = (u16*)(ws + 33554432);  // [4096][1024] bf16
  u16* xb = (u16*)(ws + 41943040);    // [4096][1024] bf16

  cvt_bf16<<<4096, 256, 0, stream>>>((const float4*)x, (u16x4*)xb);
  transpose_cvt<<<dim3(48, 16), 256, 0, stream>>>(Wqkv, WqkvT, 1024, 3072);
  transpose_cvt<<<dim3(16, 16), 256, 0, stream>>>(Wout, WoutT, 1024, 1024);
  gemm_bt_kernel<false, 128><<<dim3(24, 32), 256, 0, stream>>>(
      xb, WqkvT, bqkv, (void*)qkv, 4096, 3072, 1024);
  flash_kernel<<<512, 512, 0, stream>>>(qkv, attn);
  gemm_bt_kernel<true, 64><<<dim3(16, 32), 256, 0, stream>>>(
      attn, WoutT, bout, (void*)out, 4096, 1024, 1024);
}

// Round 8
// 196.762 us; speedup vs baseline: 1.1805x; 1.1805x over previous
//
#include <hip/hip_runtime.h>
#include <hip/hip_bf16.h>

typedef unsigned short u16;
typedef __attribute__((ext_vector_type(8))) short short8;
typedef __attribute__((ext_vector_type(4))) float f32x4;
typedef __attribute__((ext_vector_type(4))) unsigned short u16x4;

#define LOG2E 1.44269504088896340736f

// ---- helpers ---------------------------------------------------------------

__device__ __forceinline__ void gl_lds16(const void* g, void* l) {
  __builtin_amdgcn_global_load_lds(
      (__attribute__((address_space(1))) void*)g,
      (__attribute__((address_space(3))) void*)l, 16, 0, 0);
}

__device__ __forceinline__ u16 f2bf(float f) {
  union { float f; unsigned int i; } v;
  v.f = f;
  unsigned int r = v.i + 0x7fffu + ((v.i >> 16) & 1u);  // RNE
  return (u16)(r >> 16);
}

__device__ __forceinline__ unsigned int pack_bf2(float lo, float hi) {
  union { __hip_bfloat162 h2; unsigned int u; } c;
  c.h2 = __float22bfloat162_rn(make_float2(lo, hi));
  return c.u;
}

// ---- fp32 -> bf16 elementwise convert --------------------------------------

__global__ __launch_bounds__(256) void cvt_bf16(const float4* __restrict__ in,
                                                u16x4* __restrict__ out) {
  int i = blockIdx.x * 256 + threadIdx.x;
  float4 v = in[i];
  u16x4 o;
  o.x = f2bf(v.x); o.y = f2bf(v.y); o.z = f2bf(v.z); o.w = f2bf(v.w);
  out[i] = o;
}

// ---- weight transpose+convert: WT[n][k] = bf16(W[k][n]) --------------------

__global__ __launch_bounds__(256) void transpose_cvt(
    const float* __restrict__ W, u16* __restrict__ WT, int K, int N) {
  __shared__ u16 t[64][65];
  int r0 = blockIdx.y * 64, c0 = blockIdx.x * 64;
  int tx = threadIdx.x & 63, ty = threadIdx.x >> 6;
  for (int r = ty; r < 64; r += 4)
    t[r][tx] = f2bf(W[(size_t)(r0 + r) * N + c0 + tx]);
  __syncthreads();
  for (int r = ty; r < 64; r += 4)
    WT[(size_t)(c0 + r) * K + r0 + tx] = t[tx][r];
}

// ---- gemm_bt: C[M][N] = A[M][K] * Bt[N][K]^T + bias[N] ---------------------
// 128xBN tile (BN=128 or 64), BK=32, 4 waves, mfma 16x16x32 bf16

template <bool OUT_F32, int BN>
__global__ __launch_bounds__(256) void gemm_bt_kernel(
    const u16* __restrict__ A, const u16* __restrict__ Bt,
    const float* __restrict__ bias, void* __restrict__ Cout,
    int M, int N, int K) {
  constexpr int NBJ = BN / 32;
  constexpr int CHUNKS = 8 + BN / 16;
  constexpr int PER_W = CHUNKS / 4;
  __shared__ u16 As[128 * 32];
  __shared__ u16 Bs[BN * 32];
  int tid = threadIdx.x;
  int w = tid >> 6, lane = tid & 63, l15 = lane & 15, quad = lane >> 4;
  int m0 = blockIdx.y * 128, n0 = blockIdx.x * BN;
  int wm = (w & 1) * 64, wn = (w >> 1) * (BN / 2);

  f32x4 acc[4][NBJ];
#pragma unroll
  for (int i = 0; i < 4; ++i)
#pragma unroll
    for (int j = 0; j < NBJ; ++j) {
      f32x4 z = {0.f, 0.f, 0.f, 0.f};
      acc[i][j] = z;
    }

  int srow = lane >> 2;
  int scol = (lane & 3) * 8;

  for (int kt = 0; kt < K; kt += 32) {
    __syncthreads();
#pragma unroll
    for (int i = 0; i < PER_W; ++i) {
      int c = w * PER_W + i;
      if (c < 8) {
        int row = m0 + c * 16 + srow;
        gl_lds16(A + (size_t)row * K + kt + scol, As + c * 512);
      } else {
        int cc = c - 8;
        int row = n0 + cc * 16 + srow;
        gl_lds16(Bt + (size_t)row * K + kt + scol, Bs + cc * 512);
      }
    }
    __syncthreads();

    short8 af[4], bf[NBJ];
#pragma unroll
    for (int i = 0; i < 4; ++i)
      af[i] = *(const short8*)(As + (wm + i * 16 + l15) * 32 + quad * 8);
#pragma unroll
    for (int j = 0; j < NBJ; ++j)
      bf[j] = *(const short8*)(Bs + (wn + j * 16 + l15) * 32 + quad * 8);
#pragma unroll
    for (int i = 0; i < 4; ++i)
#pragma unroll
      for (int j = 0; j < NBJ; ++j)
        acc[i][j] = __builtin_amdgcn_mfma_f32_16x16x32_bf16(af[i], bf[j],
                                                            acc[i][j], 0, 0, 0);
  }

  float bv[NBJ];
#pragma unroll
  for (int j = 0; j < NBJ; ++j) bv[j] = bias[n0 + wn + j * 16 + l15];
#pragma unroll
  for (int i = 0; i < 4; ++i)
#pragma unroll
    for (int j = 0; j < NBJ; ++j) {
      int col = n0 + wn + j * 16 + l15;
#pragma unroll
      for (int r = 0; r < 4; ++r) {
        int row = m0 + wm + i * 16 + quad * 4 + r;
        float val = acc[i][j][r] + bv[j];
        if (OUT_F32)
          ((float*)Cout)[(size_t)row * N + col] = val;
        else
          ((u16*)Cout)[(size_t)row * N + col] = f2bf(val);
      }
    }
}

// ---- flash attention: ONE q-tile per block + wave-split-K ------------------
// 512-thread blocks, grid 1024 (heavy q-tiles first). Waves 0-3 = half 0
// (kt even), waves 4-7 = half 1 (kt odd). Fixed softmax shift (m=16) makes
// partials additive: O=O0+O1, l=l0+l1, merged in LDS. K staged DIRECTLY via
// global_load_lds with swizzle-precomputed SOURCE addresses (lane L reads
// global 16B-group g=(L&7)^(row&7) so the lane-contiguous DMA lands in the
// swizzled layout). V register-transposed. Double-buffered, 1 barrier/iter.
// LDS (dwords): Ks half*4096+buf*2048 | Vt 8192+half*4096+buf*2048 | Ps 16384+w*512

__global__ __launch_bounds__(512, 3) void flash_kernel(
    const u16* __restrict__ qkv, u16* __restrict__ att) {
  __shared__ unsigned int SH[20480];  // 80 KB

  int tid = threadIdx.x;
  int w = tid >> 6;    // 0..7
  int half = w >> 2;   // 0,1
  int wq = w & 3;      // q-quarter
  int lane = tid & 63, l15 = lane & 15, quad = lane >> 4;
  int bx = blockIdx.x;
  int qi = 31 - (bx >> 5);  // heavy first
  int bh = bx & 31, b = bh >> 4, h = bh & 15;
  const int jmax = (qi >> 1) + 1;

  const u16* base = qkv + (size_t)b * 2048 * 3072 + h * 64;
  const u16* kb = base + 1024;
  const u16* vb = base + 2048;

  // ones A-frag (row m=0) for the denominator tile
  short8 onesf;
#pragma unroll
  for (int j = 0; j < 8; ++j) onesf[j] = (l15 == 0) ? (short)0x3F80 : (short)0;

  // Q fragments (B-operand layout) direct from global
  short8 aq[2];
  {
    const u16* qrow = base + (size_t)(qi * 64 + wq * 16 + l15) * 3072;
    aq[0] = *(const short8*)(qrow + quad * 8);
    aq[1] = *(const short8*)(qrow + 32 + quad * 8);
  }

  // K dma source mapping: chunks L1 = wq*64+lane, L2 = L1+256
  const int L1 = wq * 64 + lane, L2 = L1 + 256;
  const int kr1_ = L1 >> 3, kg1 = (L1 & 7) ^ (kr1_ & 7);
  const int kr2_ = L2 >> 3, kg2 = (L2 & 7) ^ (kr2_ & 7);
  // V staging mapping (per half, 256 threads)
  int ht = tid & 255;
  const int vpr = ht >> 3, h7 = ht & 7, vd0 = h7 * 8;

  unsigned int* KsH = SH + half * 4096;
  unsigned int* VtH = SH + 8192 + half * 4096;
  unsigned int* Pw = SH + 16384 + w * 512;

  f32x4 o[5];
#pragma unroll
  for (int jd = 0; jd < 5; ++jd) {
    f32x4 z = {0.f, 0.f, 0.f, 0.f};
    o[jd] = z;
  }

  uint4 vr0, vr1;
  const int kt0 = half;
  if (kt0 <= qi) {
    // V tile kt0 -> regs -> LDS buf0
    vr0 = *(const uint4*)(vb + (size_t)(kt0 * 64 + 2 * vpr) * 3072 + vd0);
    vr1 = *(const uint4*)(vb + (size_t)(kt0 * 64 + 2 * vpr + 1) * 3072 + vd0);
    const u16* av = (const u16*)&vr0;
    const u16* bvp = (const u16*)&vr1;
#pragma unroll
    for (int jj = 0; jj < 8; ++jj) {
      int d = vd0 + jj;
      VtH[32 * d + (vpr ^ ((jj ^ h7) << 2))] =
          (unsigned int)av[jj] | ((unsigned int)bvp[jj] << 16);
    }
    // K tile kt0 -> LDS buf0 via dma (swizzled source)
    gl_lds16(kb + (size_t)(kt0 * 64 + kr1_) * 3072 + kg1 * 8,
             (char*)&KsH[wq * 256]);
    gl_lds16(kb + (size_t)(kt0 * 64 + kr2_) * 3072 + kg2 * 8,
             (char*)&KsH[1024 + wq * 256]);
  }
  if (kt0 + 2 <= qi) {
    vr0 = *(const uint4*)(vb + (size_t)((kt0 + 2) * 64 + 2 * vpr) * 3072 + vd0);
    vr1 = *(const uint4*)(vb + (size_t)((kt0 + 2) * 64 + 2 * vpr + 1) * 3072 + vd0);
  }

  const int psw = (l15 & 7) << 2;
  const float kscale = 0.125f * LOG2E;
  const float fshift = 16.0f;

  for (int j = 0; j < jmax; ++j) {
    int kt = 2 * j + half;
    __syncthreads();  // buf[j&1] staged; readers of buf[(j+1)&1] done
    if (kt + 2 <= qi) {
      int bufn = (j + 1) & 1;
      unsigned int* VtB = VtH + bufn * 2048;
      const u16* av = (const u16*)&vr0;
      const u16* bvp = (const u16*)&vr1;
#pragma unroll
      for (int jj = 0; jj < 8; ++jj) {
        int d = vd0 + jj;
        VtB[32 * d + (vpr ^ ((jj ^ h7) << 2))] =
            (unsigned int)av[jj] | ((unsigned int)bvp[jj] << 16);
      }
      unsigned int* KsB = KsH + bufn * 2048;
      int kn = (kt + 2) * 64;
      gl_lds16(kb + (size_t)(kn + kr1_) * 3072 + kg1 * 8, (char*)&KsB[wq * 256]);
      gl_lds16(kb + (size_t)(kn + kr2_) * 3072 + kg2 * 8,
               (char*)&KsB[1024 + wq * 256]);
    }
    if (kt + 4 <= qi) {
      int kn = (kt + 4) * 64;
      vr0 = *(const uint4*)(vb + (size_t)(kn + 2 * vpr) * 3072 + vd0);
      vr1 = *(const uint4*)(vb + (size_t)(kn + 2 * vpr + 1) * 3072 + vd0);
    }
    if (kt <= qi) {
      const unsigned int* Kb = KsH + (j & 1) * 2048;
      const unsigned int* Vb = VtH + (j & 1) * 2048;

      // S^T = K Q^T (col = q = l15, row = key)
      f32x4 s[4];
#pragma unroll
      for (int jn = 0; jn < 4; ++jn) {
        f32x4 z = {0.f, 0.f, 0.f, 0.f};
        s[jn] = z;
      }
#pragma unroll
      for (int ss = 0; ss < 2; ++ss)
#pragma unroll
        for (int jn = 0; jn < 4; ++jn) {
          int row = jn * 16 + l15;
          short8 bk = *(const short8*)&Kb[32 * row + ((16 * ss + 4 * quad) ^
                                                      ((row & 7) << 2))];
          s[jn] = __builtin_amdgcn_mfma_f32_16x16x32_bf16(bk, aq[ss], s[jn],
                                                          0, 0, 0);
        }

      // P = exp2(s*kscale - 16), diagonal-masked
      bool diag = (kt == qi);
      int qloc = wq * 16 + l15;
#pragma unroll
      for (int jn = 0; jn < 4; ++jn) {
        float pv[4];
#pragma unroll
        for (int r = 0; r < 4; ++r) {
          float sv = s[jn][r];
          if (diag && (jn * 16 + quad * 4 + r > qloc)) sv = -1e30f;
          pv[r] = exp2f(fmaf(sv, kscale, -fshift));
        }
        uint2 dd = make_uint2(pack_bf2(pv[0], pv[1]), pack_bf2(pv[2], pv[3]));
        *(uint2*)&Pw[32 * l15 + (((jn << 3) + (quad << 1)) ^ psw)] = dd;
      }

      // O^T += Vt P^T (+ ones-frag tile accumulates l)
#pragma unroll
      for (int ss = 0; ss < 2; ++ss) {
        short8 pf = *(const short8*)&Pw[32 * l15 +
                                        (((ss << 4) + (quad << 2)) ^ psw)];
#pragma unroll
        for (int jd = 0; jd < 4; ++jd) {
          int vrow = jd * 16 + l15;
          int f = (vrow & 7) ^ ((vrow >> 3) & 7);
          short8 bvv = *(const short8*)&Vb[32 * vrow + (((ss << 4) +
                                                         (quad << 2)) ^
                                                        (f << 2))];
          o[jd] = __builtin_amdgcn_mfma_f32_16x16x32_bf16(bvv, pf, o[jd],
                                                          0, 0, 0);
        }
        o[4] = __builtin_amdgcn_mfma_f32_16x16x32_bf16(onesf, pf, o[4], 0, 0, 0);
      }
    }
  }

  // ---- merge halves (partials additive under fixed shift) ----
  __syncthreads();
  float* OM = (float*)SH;             // [q=64][68]
  float* LM = (float*)(SH + 4352);    // [64]
  int q = wq * 16 + l15;
  if (half == 0) {
#pragma unroll
    for (int jd = 0; jd < 4; ++jd)
      *(float4*)&OM[q * 68 + jd * 16 + quad * 4] = *(float4*)&o[jd];
    if (quad == 0) LM[q] = o[4][0];
  }
  __syncthreads();
  if (half == 1) {
    float lr = __shfl(o[4][0], l15, 64) + LM[q];
    float inv = 1.f / lr;
    size_t row = (size_t)b * 2048 + qi * 64 + q;
    u16* orow = att + row * 1024 + h * 64 + quad * 4;
#pragma unroll
    for (int jd = 0; jd < 4; ++jd) {
      float4 pa = *(float4*)&OM[q * 68 + jd * 16 + quad * 4];
      uint2 dd = make_uint2(pack_bf2((o[jd][0] + pa.x) * inv,
                                     (o[jd][1] + pa.y) * inv),
                            pack_bf2((o[jd][2] + pa.z) * inv,
                                     (o[jd][3] + pa.w) * inv));
      *(uint2*)(orow + jd * 16) = dd;
    }
  }
}

// ---- launch ----------------------------------------------------------------

extern "C" void kernel_launch(void* const* d_in, const int* in_sizes, int n_in,
                              void* d_out, int out_size, void* d_ws,
                              size_t ws_size, hipStream_t stream) {
  const float* x = (const float*)d_in[0];
  const float* Wqkv = (const float*)d_in[1];
  const float* bqkv = (const float*)d_in[2];
  const float* Wout = (const float*)d_in[3];
  const float* bout = (const float*)d_in[4];
  float* out = (float*)d_out;

  char* ws = (char*)d_ws;
  u16* WqkvT = (u16*)(ws);            // [3072][1024] bf16
  u16* WoutT = (u16*)(ws + 6291456);  // [1024][1024] bf16
  u16* qkv = (u16*)(ws + 8388608);    // [4096][3072] bf16
  u16* attn = (u16*)(ws + 33554432);  // [4096][1024] bf16
  u16* xb = (u16*)(ws + 41943040);    // [4096][1024] bf16

  cvt_bf16<<<4096, 256, 0, stream>>>((const float4*)x, (u16x4*)xb);
  transpose_cvt<<<dim3(48, 16), 256, 0, stream>>>(Wqkv, WqkvT, 1024, 3072);
  transpose_cvt<<<dim3(16, 16), 256, 0, stream>>>(Wout, WoutT, 1024, 1024);
  gemm_bt_kernel<false, 128><<<dim3(24, 32), 256, 0, stream>>>(
      xb, WqkvT, bqkv, (void*)qkv, 4096, 3072, 1024);
  flash_kernel<<<1024, 512, 0, stream>>>(qkv, attn);
  gemm_bt_kernel<true, 64><<<dim3(16, 32), 256, 0, stream>>>(
      attn, WoutT, bout, (void*)out, 4096, 1024, 1024);
}

// Round 9
// 183.825 us; speedup vs baseline: 1.2636x; 1.0704x over previous
//
#include <hip/hip_runtime.h>
#include <hip/hip_bf16.h>

typedef unsigned short u16;
typedef __attribute__((ext_vector_type(8))) short short8;
typedef __attribute__((ext_vector_type(4))) float f32x4;
typedef __attribute__((ext_vector_type(4))) unsigned short u16x4;

#define LOG2E 1.44269504088896340736f

// ---- helpers ---------------------------------------------------------------

__device__ __forceinline__ void gl_lds16(const void* g, void* l) {
  __builtin_amdgcn_global_load_lds(
      (__attribute__((address_space(1))) void*)g,
      (__attribute__((address_space(3))) void*)l, 16, 0, 0);
}

__device__ __forceinline__ float exp2_fast(float x) {
#if __has_builtin(__builtin_amdgcn_exp2f)
  return __builtin_amdgcn_exp2f(x);  // bare v_exp_f32
#else
  return exp2f(x);
#endif
}

__device__ __forceinline__ u16 f2bf(float f) {
  union { float f; unsigned int i; } v;
  v.f = f;
  unsigned int r = v.i + 0x7fffu + ((v.i >> 16) & 1u);  // RNE
  return (u16)(r >> 16);
}

__device__ __forceinline__ unsigned int pack_bf2(float lo, float hi) {
  union { __hip_bfloat162 h2; unsigned int u; } c;
  c.h2 = __float22bfloat162_rn(make_float2(lo, hi));
  return c.u;
}

// ---- fused prep: x->bf16 cvt + both weight transposes ----------------------

__global__ __launch_bounds__(256) void prep_kernel(
    const float4* __restrict__ x, u16x4* __restrict__ xb,
    const float* __restrict__ Wqkv, u16* __restrict__ WqkvT,
    const float* __restrict__ Wout, u16* __restrict__ WoutT) {
  __shared__ u16 t[64][65];
  int bid = blockIdx.x, tid = threadIdx.x;
  if (bid < 4096) {
    int i = bid * 256 + tid;
    float4 v = x[i];
    u16x4 o;
    o.x = f2bf(v.x); o.y = f2bf(v.y); o.z = f2bf(v.z); o.w = f2bf(v.w);
    xb[i] = o;
    return;
  }
  const float* W;
  u16* WT;
  int K = 1024, N, bxx, byy;
  if (bid < 4864) {
    int tt = bid - 4096;
    W = Wqkv; WT = WqkvT; N = 3072; bxx = tt % 48; byy = tt / 48;
  } else {
    int tt = bid - 4864;
    W = Wout; WT = WoutT; N = 1024; bxx = tt % 16; byy = tt / 16;
  }
  int r0 = byy * 64, c0 = bxx * 64;
  int tx = tid & 63, ty = tid >> 6;
  for (int r = ty; r < 64; r += 4)
    t[r][tx] = f2bf(W[(size_t)(r0 + r) * N + c0 + tx]);
  __syncthreads();
  for (int r = ty; r < 64; r += 4)
    WT[(size_t)(c0 + r) * K + r0 + tx] = t[tx][r];
}

// ---- gemm_bt: C[M][N] = A[M][K] * Bt[N][K]^T + bias[N], BK=64 --------------
// Staging via gl_lds16 with swizzle-precomputed SOURCE groups: lane reads
// global group (lane&7)^(row&7) so the lane-contiguous DMA lands XOR-swizzled;
// frag reads then use addr ^ ((row&7)*8) -> conflict-free b128.

template <bool OUT_F32, int BN>
__global__ __launch_bounds__(256) void gemm_bt_kernel(
    const u16* __restrict__ A, const u16* __restrict__ Bt,
    const float* __restrict__ bias, void* __restrict__ Cout,
    int M, int N, int K) {
  constexpr int NBJ = BN / 32;
  constexpr int CH_A = 16;           // 128 rows / 8
  constexpr int CH_B = BN / 8;
  constexpr int PER_W = (CH_A + CH_B) / 4;
  __shared__ u16 As[128 * 64];
  __shared__ u16 Bs[BN * 64];
  int tid = threadIdx.x;
  int w = tid >> 6, lane = tid & 63, l15 = lane & 15, quad = lane >> 4;
  int m0 = blockIdx.y * 128, n0 = blockIdx.x * BN;
  int wm = (w & 1) * 64, wn = (w >> 1) * (BN / 2);

  f32x4 acc[4][NBJ];
#pragma unroll
  for (int i = 0; i < 4; ++i)
#pragma unroll
    for (int j = 0; j < NBJ; ++j) {
      f32x4 z = {0.f, 0.f, 0.f, 0.f};
      acc[i][j] = z;
    }

  int r8 = lane >> 3;                 // row within 8-row chunk
  int sw = ((lane & 7) ^ r8) * 8;     // swizzled source col (u16)

  for (int kt = 0; kt < K; kt += 64) {
    __syncthreads();
#pragma unroll
    for (int i = 0; i < PER_W; ++i) {
      int c = w * PER_W + i;
      if (c < CH_A) {
        int row = m0 + c * 8 + r8;
        gl_lds16(A + (size_t)row * K + kt + sw, As + c * 512);
      } else {
        int cc = c - CH_A;
        int row = n0 + cc * 8 + r8;
        gl_lds16(Bt + (size_t)row * K + kt + sw, Bs + cc * 512);
      }
    }
    __syncthreads();

#pragma unroll
    for (int kh = 0; kh < 2; ++kh) {
      short8 af[4], bf[NBJ];
#pragma unroll
      for (int i = 0; i < 4; ++i) {
        int R = wm + i * 16 + l15;
        af[i] = *(const short8*)(As + R * 64 +
                                 ((kh * 32 + quad * 8) ^ ((R & 7) * 8)));
      }
#pragma unroll
      for (int j = 0; j < NBJ; ++j) {
        int R = wn + j * 16 + l15;
        bf[j] = *(const short8*)(Bs + R * 64 +
                                 ((kh * 32 + quad * 8) ^ ((R & 7) * 8)));
      }
#pragma unroll
      for (int i = 0; i < 4; ++i)
#pragma unroll
        for (int j = 0; j < NBJ; ++j)
          acc[i][j] = __builtin_amdgcn_mfma_f32_16x16x32_bf16(af[i], bf[j],
                                                              acc[i][j], 0, 0, 0);
    }
  }

  float bv[NBJ];
#pragma unroll
  for (int j = 0; j < NBJ; ++j) bv[j] = bias[n0 + wn + j * 16 + l15];
#pragma unroll
  for (int i = 0; i < 4; ++i)
#pragma unroll
    for (int j = 0; j < NBJ; ++j) {
      int col = n0 + wn + j * 16 + l15;
#pragma unroll
      for (int r = 0; r < 4; ++r) {
        int row = m0 + wm + i * 16 + quad * 4 + r;
        float val = acc[i][j][r] + bv[j];
        if (OUT_F32)
          ((float*)Cout)[(size_t)row * N + col] = val;
        else
          ((u16*)Cout)[(size_t)row * N + col] = f2bf(val);
      }
    }
}

// ---- flash attention: paired 128-row q-supertiles + wave-split-K -----------
// Grid 256 = 1 block/CU, uniform work (17 units/half). Block 512 = 8 waves:
// waves 0-3 kt even, 4-7 kt odd. Each wave owns 32 q (2 subtiles of 16) ->
// every K/V LDS frag read feeds 2 MFMAs. Both strips share each staged tile.
// Fixed softmax shift 16; denominator via per-lane sums (+2 shuffles at end).
// Single-buffered K/V per half, register prefetch, 2 barriers/iter.
// LDS (dwords): Ks half*2048 | Vt 4096+half*2048 | P 8192+w*1024+qsub*512

__global__ __launch_bounds__(512, 2) void flash_kernel(
    const u16* __restrict__ qkv, u16* __restrict__ att) {
  __shared__ unsigned int SH[16384];  // 64 KB

  int tid = threadIdx.x;
  int w = tid >> 6, half = w >> 2, wq = w & 3;
  int lane = tid & 63, l15 = lane & 15, quad = lane >> 4;
  int bx = blockIdx.x;
  int p = bx >> 5, bh = bx & 31, b = bh >> 4, h = bh & 15;
  const int qs[2] = {15 - p, p};
  const int kmax0 = 2 * qs[0] + 1, kmax1 = 2 * p + 1;
  const int jmax = 16 - p;

  const u16* base = qkv + (size_t)b * 2048 * 3072 + h * 64;
  const u16* kb = base + 1024;
  const u16* vb = base + 2048;

  int ht = tid & 255;
  const int krow = ht >> 3, h7 = ht & 7;

  unsigned int* KsH = SH + half * 2048;
  unsigned int* VtH = SH + 4096 + half * 2048;
  unsigned int* Pw = SH + 8192 + w * 1024;

  // prefetch tile kt = half
  uint4 kr0 = *(const uint4*)(kb + (size_t)(half * 64 + krow) * 3072 + h7 * 8);
  uint4 kr1 = *(const uint4*)(kb + (size_t)(half * 64 + krow + 32) * 3072 + h7 * 8);
  uint4 vr0 = *(const uint4*)(vb + (size_t)(half * 64 + 2 * krow) * 3072 + h7 * 8);
  uint4 vr1 = *(const uint4*)(vb + (size_t)(half * 64 + 2 * krow + 1) * 3072 + h7 * 8);

  f32x4 o[2][2][4];
#pragma unroll
  for (int t = 0; t < 2; ++t)
#pragma unroll
    for (int qsub = 0; qsub < 2; ++qsub)
#pragma unroll
      for (int jd = 0; jd < 4; ++jd) {
        f32x4 z = {0.f, 0.f, 0.f, 0.f};
        o[t][qsub][jd] = z;
      }
  float lsum[2][2] = {0.f, 0.f, 0.f, 0.f};

  const int psw = (l15 & 7) << 2;
  const float kscale = 0.125f * LOG2E;

  for (int j = 0; j < jmax; ++j) {
    int kt = 2 * j + half;
    __syncthreads();  // readers of previous tile done
    // stage K (2 x b128, swizzled) + V^T (8 packed b32)
    *(uint4*)&KsH[32 * krow + ((4 * h7) ^ ((krow & 7) << 2))] = kr0;
    {
      int r1 = krow + 32;
      *(uint4*)&KsH[32 * r1 + ((4 * h7) ^ ((r1 & 7) << 2))] = kr1;
    }
    {
      const u16* av = (const u16*)&vr0;
      const u16* bvp = (const u16*)&vr1;
#pragma unroll
      for (int jj = 0; jj < 8; ++jj) {
        int d = h7 * 8 + jj;
        VtH[32 * d + (krow ^ ((jj ^ h7) << 2))] =
            (unsigned int)av[jj] | ((unsigned int)bvp[jj] << 16);
      }
    }
    __syncthreads();  // staging visible
    if (j + 1 < jmax) {  // prefetch next tile (hidden behind compute)
      int kn = (kt + 2) * 64;
      kr0 = *(const uint4*)(kb + (size_t)(kn + krow) * 3072 + h7 * 8);
      kr1 = *(const uint4*)(kb + (size_t)(kn + krow + 32) * 3072 + h7 * 8);
      vr0 = *(const uint4*)(vb + (size_t)(kn + 2 * krow) * 3072 + h7 * 8);
      vr1 = *(const uint4*)(vb + (size_t)(kn + 2 * krow + 1) * 3072 + h7 * 8);
    }

#pragma unroll
    for (int t = 0; t < 2; ++t) {
      int km = t ? kmax1 : kmax0;
      if (kt > km) continue;               // strip done (wave-uniform)
      bool last = (kt == km);
      if (last && wq < 2) continue;        // fully-masked waves at final tile
      bool domask = last || ((kt == km - 1) && wq < 2);
      int qloc = ((last ? (wq - 2) : wq) << 5) + l15;  // valid when domask

      // Q fragments for both subtiles (L2-hot re-read; no persistent regs)
      const u16* qtb = base + (size_t)(qs[t] * 128 + wq * 32 + l15) * 3072;
      short8 aq00 = *(const short8*)(qtb + quad * 8);
      short8 aq01 = *(const short8*)(qtb + 32 + quad * 8);
      short8 aq10 = *(const short8*)(qtb + 16 * 3072 + quad * 8);
      short8 aq11 = *(const short8*)(qtb + 16 * 3072 + 32 + quad * 8);

      // S^T = K Q^T for both subtiles; each bk read feeds 2 MFMAs
      f32x4 s0[4], s1[4];
#pragma unroll
      for (int jn = 0; jn < 4; ++jn) {
        f32x4 z = {0.f, 0.f, 0.f, 0.f};
        s0[jn] = z;
        s1[jn] = z;
      }
#pragma unroll
      for (int ss = 0; ss < 2; ++ss) {
        short8 a0 = ss ? aq01 : aq00;
        short8 a1 = ss ? aq11 : aq10;
#pragma unroll
        for (int jn = 0; jn < 4; ++jn) {
          int row = jn * 16 + l15;
          short8 bk = *(const short8*)&KsH[32 * row + ((16 * ss + 4 * quad) ^
                                                       ((row & 7) << 2))];
          s0[jn] = __builtin_amdgcn_mfma_f32_16x16x32_bf16(bk, a0, s0[jn], 0, 0, 0);
          s1[jn] = __builtin_amdgcn_mfma_f32_16x16x32_bf16(bk, a1, s1[jn], 0, 0, 0);
        }
      }

      // P = exp2(s*kscale - 16) (masked), packed b64 writes + lane sums
#pragma unroll
      for (int qsub = 0; qsub < 2; ++qsub) {
        int qq = qloc + qsub * 16;
        float ls = 0.f;
#pragma unroll
        for (int jn = 0; jn < 4; ++jn) {
          f32x4 sv = qsub ? s1[jn] : s0[jn];
          float pv[4];
#pragma unroll
          for (int r = 0; r < 4; ++r) {
            float e = exp2_fast(fmaf(sv[r], kscale, -16.0f));
            if (domask && (jn * 16 + quad * 4 + r > qq)) e = 0.f;
            pv[r] = e;
            ls += e;
          }
          uint2 dd = make_uint2(pack_bf2(pv[0], pv[1]), pack_bf2(pv[2], pv[3]));
          *(uint2*)&Pw[qsub * 512 + 32 * l15 +
                       (((jn << 3) + (quad << 1)) ^ psw)] = dd;
        }
        lsum[t][qsub] += ls;
      }

      // O^T += Vt P^T; each bvv read feeds 2 MFMAs
#pragma unroll
      for (int ss = 0; ss < 2; ++ss) {
        short8 pf0 = *(const short8*)&Pw[32 * l15 +
                                         (((ss << 4) + (quad << 2)) ^ psw)];
        short8 pf1 = *(const short8*)&Pw[512 + 32 * l15 +
                                         (((ss << 4) + (quad << 2)) ^ psw)];
#pragma unroll
        for (int jd = 0; jd < 4; ++jd) {
          int vrow = jd * 16 + l15;
          int f = (vrow & 7) ^ ((vrow >> 3) & 7);
          short8 bvv = *(const short8*)&VtH[32 * vrow +
                                            (((ss << 4) + (quad << 2)) ^ (f << 2))];
          o[t][0][jd] =
              __builtin_amdgcn_mfma_f32_16x16x32_bf16(bvv, pf0, o[t][0][jd], 0, 0, 0);
          o[t][1][jd] =
              __builtin_amdgcn_mfma_f32_16x16x32_bf16(bvv, pf1, o[t][1][jd], 0, 0, 0);
        }
      }
    }
  }

  // full denominator per (t,qsub): sum the 4 quads
  float lf[2][2];
#pragma unroll
  for (int t = 0; t < 2; ++t)
#pragma unroll
    for (int qsub = 0; qsub < 2; ++qsub) {
      float v = lsum[t][qsub];
      v += __shfl_xor(v, 16, 64);
      v += __shfl_xor(v, 32, 64);
      lf[t][qsub] = v;
    }

  // ---- merge halves in LDS (partials additive under fixed shift) ----
  float* OM = (float*)SH;            // [q=128][68]
  float* LM = (float*)(SH + 8704);   // [128]
  __syncthreads();
#pragma unroll
  for (int t = 0; t < 2; ++t) {
    if (half == 0) {
#pragma unroll
      for (int qsub = 0; qsub < 2; ++qsub) {
        int q = wq * 32 + qsub * 16 + l15;
#pragma unroll
        for (int jd = 0; jd < 4; ++jd)
          *(float4*)&OM[q * 68 + jd * 16 + quad * 4] = *(float4*)&o[t][qsub][jd];
        if (quad == 0) LM[q] = lf[t][qsub];
      }
    }
    __syncthreads();
    if (half == 1) {
#pragma unroll
      for (int qsub = 0; qsub < 2; ++qsub) {
        int q = wq * 32 + qsub * 16 + l15;
        float lr = lf[t][qsub] + LM[q];
        float inv = 1.f / lr;
        size_t row = (size_t)b * 2048 + qs[t] * 128 + q;
        u16* orow = att + row * 1024 + h * 64 + quad * 4;
#pragma unroll
        for (int jd = 0; jd < 4; ++jd) {
          float4 pa = *(float4*)&OM[q * 68 + jd * 16 + quad * 4];
          uint2 dd = make_uint2(pack_bf2((o[t][qsub][jd][0] + pa.x) * inv,
                                         (o[t][qsub][jd][1] + pa.y) * inv),
                                pack_bf2((o[t][qsub][jd][2] + pa.z) * inv,
                                         (o[t][qsub][jd][3] + pa.w) * inv));
          *(uint2*)(orow + jd * 16) = dd;
        }
      }
    }
    __syncthreads();
  }
}

// ---- launch ----------------------------------------------------------------

extern "C" void kernel_launch(void* const* d_in, const int* in_sizes, int n_in,
                              void* d_out, int out_size, void* d_ws,
                              size_t ws_size, hipStream_t stream) {
  const float* x = (const float*)d_in[0];
  const float* Wqkv = (const float*)d_in[1];
  const float* bqkv = (const float*)d_in[2];
  const float* Wout = (const float*)d_in[3];
  const float* bout = (const float*)d_in[4];
  float* out = (float*)d_out;

  char* ws = (char*)d_ws;
  u16* WqkvT = (u16*)(ws);            // [3072][1024] bf16
  u16* WoutT = (u16*)(ws + 6291456);  // [1024][1024] bf16
  u16* qkv = (u16*)(ws + 8388608);    // [4096][3072] bf16
  u16* attn = (u16*)(ws + 33554432);  // [4096][1024] bf16
  u16* xb = (u16*)(ws + 41943040);    // [4096][1024] bf16

  prep_kernel<<<5120, 256, 0, stream>>>((const float4*)x, (u16x4*)xb, Wqkv,
                                        WqkvT, Wout, WoutT);
  gemm_bt_kernel<false, 128><<<dim3(24, 32), 256, 0, stream>>>(
      xb, WqkvT, bqkv, (void*)qkv, 4096, 3072, 1024);
  flash_kernel<<<256, 512, 0, stream>>>(qkv, attn);
  gemm_bt_kernel<true, 64><<<dim3(16, 32), 256, 0, stream>>>(
      attn, WoutT, bout, (void*)out, 4096, 1024, 1024);
}